// Round 11
// baseline (3102.082 us; speedup 1.0000x reference)
//
#include <hip/hip_runtime.h>
#include <math.h>

#define TPB 256
#define TILE 16
#define OCB 8
#define CORR_CS 32

enum { M_BIAS=0, M_BIAS_RELU=1, M_BN_RELU=2, M_SIGAFF=3 };

// ---------------- generic direct conv (small layers), optional channel-split -----
template<int K>
__global__ __launch_bounds__(TPB)
void conv_k(const float* __restrict__ in, long inb,
            float* __restrict__ out, long outb,
            const float* __restrict__ w,
            const float* __restrict__ a1, const float* __restrict__ a2,
            int Cin, int Cout, int H, int W, int mode, int CS)
{
    constexpr int PAD = K/2;
    constexpr int S = TILE + K - 1;
    __shared__ float tile[S*S];
    __shared__ float wl[OCB*K*K];
    int tilesX = (W + TILE-1)/TILE;
    int tY = blockIdx.x / tilesX, tX = blockIdx.x % tilesX;
    int oc0 = blockIdx.y * OCB;
    int zz = blockIdx.z;
    int cs = zz % CS, b = zz / CS;
    int c0 = (cs*Cin)/CS, c1 = ((cs+1)*Cin)/CS;
    int tid = threadIdx.x;
    int ty = tid / TILE, tx = tid % TILE;
    int y = tY*TILE+ty, x = tX*TILE+tx;
    int oy0 = tY*TILE - PAD, ox0 = tX*TILE - PAD;
    int ocmax = Cout - oc0; if (ocmax > OCB) ocmax = OCB;
    float acc[OCB];
#pragma unroll
    for (int o=0;o<OCB;o++) acc[o]=0.f;
    const float* inp = in + (long)b*inb;
    const int HW = H*W;

    for (int c=c0;c<c1;c++){
        __syncthreads();
        const float* ic = inp + (long)c*HW;
        for (int idx=tid; idx<S*S; idx+=TPB){
            int sy = oy0 + idx/S, sx = ox0 + idx%S;
            tile[idx] = (sy>=0 && sy<H && sx>=0 && sx<W) ? ic[sy*W+sx] : 0.f;
        }
        if (tid < ocmax*(K*K)){
            int o = tid/(K*K), k = tid - o*(K*K);
            wl[o*(K*K)+k] = w[((long)(oc0+o)*Cin + c)*(K*K) + k];
        }
        __syncthreads();
        for (int k=0;k<K*K;k++){
            float xv = tile[(ty + k/K)*S + tx + k%K];
            for (int o=0;o<ocmax;o++)
                acc[o] = fmaf(xv, wl[o*(K*K)+k], acc[o]);
        }
    }

    if (y<H && x<W){
        if (CS==1){
            for (int o=0;o<ocmax;o++){
                int oc = oc0+o;
                float v = acc[o];
                if (mode==M_BIAS) { v += a1[oc]; }
                else if (mode==M_BIAS_RELU) { v += a1[oc]; v = fmaxf(v,0.f); }
                else if (mode==M_BN_RELU) { v = v / sqrtf(1.0f+1e-5f) * a1[oc] + a2[oc]; v = fmaxf(v,0.f); }
                else { v += a1[oc]; float s = 1.f/(1.f+expf(-v)); v = (8.f*s - 4.f)*8.f; }
                out[(long)b*outb + (long)oc*HW + (long)y*W + x] = v;
            }
        } else {
            for (int o=0;o<ocmax;o++)
                out[(((long)(b*CS+cs)*Cout + (oc0+o))*(long)HW) + (long)y*W + x] = acc[o];
        }
    }
}

// ---------------- specialized 3x3 conv for 64x64 planes (4 oc/thread) ------------
#define C3S 76
__global__ __launch_bounds__(TPB)
void conv3_64(const float* __restrict__ in, long inb,
              float* __restrict__ out, long outb,
              const float* __restrict__ w,
              const float* __restrict__ a1, const float* __restrict__ a2,
              int Cin, int Cout, int mode, int CS, int wCin, int wskip)
{
    __shared__ __align__(16) float slds[34*C3S];
    __shared__ __align__(16) float wlds[9*4];
    int ytile = blockIdx.x;
    int oc0 = blockIdx.y*4;
    int zz = blockIdx.z;
    int cs = zz % CS, b = zz / CS;
    int c0 = (cs*Cin)/CS, c1 = ((cs+1)*Cin)/CS;
    int tid = threadIdx.x;
    int tx = tid >> 5, ty = tid & 31;
    int y0 = ytile*32;
    const long wstr = (long)wCin*9;

    for (int i=tid;i<34*12;i+=TPB){
        int row=i/12, j=i-row*12;
        int col = (j<4)? j : 64+j;
        slds[row*C3S+col] = 0.f;
    }

    float acc[8][4];
#pragma unroll
    for (int p=0;p<8;p++)
#pragma unroll
        for (int o=0;o<4;o++) acc[p][o]=0.f;

    for (int c=c0;c<c1;++c){
        __syncthreads();
        const float* ic = in + (long)b*inb + ((long)c<<12);
        for (int i=tid;i<544;i+=TPB){
            int row=i>>4, q=i&15;
            int gy = y0-1+row;
            float4 v = make_float4(0.f,0.f,0.f,0.f);
            if (gy>=0 && gy<64) v = *(const float4*)(ic + (gy<<6) + q*4);
            *(float4*)(slds + row*C3S + 4 + q*4) = v;
        }
        int cw = (wskip && c>=22) ? c+38 : c;
        if (tid<36){
            int o=tid/9, k=tid-o*9;
            wlds[k*4+o] = w[(long)(oc0+o)*wstr + (long)cw*9 + k];
        }
        __syncthreads();

#pragma unroll
        for (int r=0;r<3;r++){
            const float* srow = slds + (ty+r)*C3S + tx*8;
            float4 r0 = *(const float4*)(srow);
            float4 r1 = *(const float4*)(srow+4);
            float4 r2 = *(const float4*)(srow+8);
            float4 r3 = *(const float4*)(srow+12);
            float t[10];
            t[0]=r0.w;
            t[1]=r1.x; t[2]=r1.y; t[3]=r1.z; t[4]=r1.w;
            t[5]=r2.x; t[6]=r2.y; t[7]=r2.z; t[8]=r2.w;
            t[9]=r3.x;
#pragma unroll
            for (int k=0;k<3;k++){
                float4 w4 = *(const float4*)(wlds + (r*3+k)*4);
#pragma unroll
                for (int p=0;p<8;p++){
                    acc[p][0] = fmaf(t[p+k], w4.x, acc[p][0]);
                    acc[p][1] = fmaf(t[p+k], w4.y, acc[p][1]);
                    acc[p][2] = fmaf(t[p+k], w4.z, acc[p][2]);
                    acc[p][3] = fmaf(t[p+k], w4.w, acc[p][3]);
                }
            }
        }
    }

    int y = y0+ty, x = tx*8;
    if (CS==1){
#pragma unroll
        for (int o=0;o<4;o++){
            int oc = oc0+o;
            float bb=0.f, gg=1.f;
            if (mode==M_BN_RELU){ gg=a1[oc]; bb=a2[oc]; }
            else { bb=a1[oc]; }
            float v[8];
#pragma unroll
            for (int p=0;p<8;p++){
                float u = acc[p][o];
                if (mode==M_BIAS) u += bb;
                else if (mode==M_BIAS_RELU){ u += bb; u = fmaxf(u,0.f); }
                else if (mode==M_BN_RELU){ u = u / sqrtf(1.0f+1e-5f) * gg + bb; u = fmaxf(u,0.f); }
                v[p] = u;
            }
            float* op = out + (long)b*outb + ((long)oc<<12) + (y<<6) + x;
            *(float4*)(op)   = make_float4(v[0],v[1],v[2],v[3]);
            *(float4*)(op+4) = make_float4(v[4],v[5],v[6],v[7]);
        }
    } else {
#pragma unroll
        for (int o=0;o<4;o++){
            float* op = out + (((long)(b*CS+cs)*Cout + (oc0+o))<<12) + (y<<6) + x;
            *(float4*)(op)   = make_float4(acc[0][o],acc[1][o],acc[2][o],acc[3][o]);
            *(float4*)(op+4) = make_float4(acc[4][o],acc[5][o],acc[6][o],acc[7][o]);
        }
    }
}

// ---------------- 3x3 conv, 64x64 planes, 8 oc/thread, 3xb128 window -------------
// 128 thr = 8tx * 16ty; 16-row tiles; pad=5 so the 10-word window is 16B-aligned
// (3 aligned b128 reads/row). Always writes channel-split partials.
__global__ __launch_bounds__(128)
void conv3w8(const float* __restrict__ in, long inb,
             float* __restrict__ out,
             const float* __restrict__ w,
             int Cin, int Cout, int CS, int wCin, int wskip)
{
    __shared__ __align__(16) float slds[18*C3S];
    __shared__ __align__(16) float wlds[9*8];
    int ytile = blockIdx.x;            // 0..3 (16-row tiles)
    int oc0 = blockIdx.y*8;
    int zz = blockIdx.z;
    int cs = zz % CS, b = zz / CS;
    int c0 = (cs*Cin)/CS, c1 = ((cs+1)*Cin)/CS;
    int tid = threadIdx.x;
    int tx = tid & 7, ty = tid >> 3;   // ty 0..15
    int y0 = ytile*16;
    const long wstr = (long)wCin*9;

    // zero pad cols 0..4 and 69..75 for all 18 staged rows
    for (int i=tid;i<18*12;i+=128){
        int row=i/12, j=i-row*12;
        int col = (j<5)? j : 64+j;     // j=5..11 -> 69..75
        slds[row*C3S+col] = 0.f;
    }

    float acc[8][8];
#pragma unroll
    for (int p=0;p<8;p++)
#pragma unroll
        for (int o=0;o<8;o++) acc[p][o]=0.f;

    for (int c=c0;c<c1;++c){
        __syncthreads();
        const float* ic = in + (long)b*inb + ((long)c<<12);
        for (int i=tid;i<288;i+=128){
            int row=i>>4, q=i&15;
            int gy = y0-1+row;
            float4 v = make_float4(0.f,0.f,0.f,0.f);
            if (gy>=0 && gy<64) v = *(const float4*)(ic + (gy<<6) + q*4);
            float* d = slds + row*C3S + 5 + q*4;
            d[0]=v.x; d[1]=v.y; d[2]=v.z; d[3]=v.w;
        }
        int cw = (wskip && c>=22) ? c+38 : c;
        if (tid<72){
            int o=tid/9, k=tid-o*9;
            wlds[k*8+o] = w[(long)(oc0+o)*wstr + (long)cw*9 + k];
        }
        __syncthreads();

#pragma unroll
        for (int r=0;r<3;r++){
            const float* srow = slds + (ty+r)*C3S + tx*8 + 4;
            float4 ra = *(const float4*)(srow);
            float4 rb = *(const float4*)(srow+4);
            float4 rc = *(const float4*)(srow+8);
            float t[12];
            t[0]=ra.x; t[1]=ra.y; t[2]=ra.z; t[3]=ra.w;
            t[4]=rb.x; t[5]=rb.y; t[6]=rb.z; t[7]=rb.w;
            t[8]=rc.x; t[9]=rc.y; t[10]=rc.z; t[11]=rc.w;
#pragma unroll
            for (int k=0;k<3;k++){
                float4 wa = *(const float4*)(wlds + (r*3+k)*8);
                float4 wb = *(const float4*)(wlds + (r*3+k)*8 + 4);
#pragma unroll
                for (int p=0;p<8;p++){
                    float xv = t[p+k];
                    acc[p][0] = fmaf(xv, wa.x, acc[p][0]);
                    acc[p][1] = fmaf(xv, wa.y, acc[p][1]);
                    acc[p][2] = fmaf(xv, wa.z, acc[p][2]);
                    acc[p][3] = fmaf(xv, wa.w, acc[p][3]);
                    acc[p][4] = fmaf(xv, wb.x, acc[p][4]);
                    acc[p][5] = fmaf(xv, wb.y, acc[p][5]);
                    acc[p][6] = fmaf(xv, wb.z, acc[p][6]);
                    acc[p][7] = fmaf(xv, wb.w, acc[p][7]);
                }
            }
        }
    }

    int y = y0+ty, x = tx*8;
#pragma unroll
    for (int o=0;o<8;o++){
        float* op = out + (((long)(b*CS+cs)*Cout + (oc0+o))<<12) + (y<<6) + x;
        *(float4*)(op)   = make_float4(acc[0][o],acc[1][o],acc[2][o],acc[3][o]);
        *(float4*)(op+4) = make_float4(acc[4][o],acc[5][o],acc[6][o],acc[7][o]);
    }
}

// ---------------- partial-sum reduce + bias/bn/act -------------------------------
__global__ __launch_bounds__(TPB)
void convred_k(const float* __restrict__ part, float* __restrict__ out, long outb,
               const float* __restrict__ a1, const float* __restrict__ a2,
               int Cout, int HW, int CS, int mode)
{
    long total = (long)2*Cout*HW;
    long i = (long)blockIdx.x*TPB + threadIdx.x;
    if (i>=total) return;
    int px = (int)(i % HW); long t = i / HW;
    int oc = (int)(t % Cout); int b = (int)(t / Cout);
    float s = 0.f;
    for (int cs=0;cs<CS;cs++) s += part[(((long)(b*CS+cs)*Cout + oc)*(long)HW) + px];
    if (mode==M_BIAS) s += a1[oc];
    else if (mode==M_BIAS_RELU){ s += a1[oc]; s = fmaxf(s,0.f); }
    else { s = s / sqrtf(1.0f+1e-5f) * a1[oc] + a2[oc]; s = fmaxf(s,0.f); }
    out[(long)b*outb + (long)oc*HW + px] = s;
}

// ---------------- bilinear resize, align_corners=True, optional add ---------------
__global__ __launch_bounds__(TPB)
void resize_k(const float* __restrict__ in, long inb, int hi, int wi,
              float* __restrict__ out, long outb, int ho, int wo,
              const float* __restrict__ add, long addb,
              int C, int B, float rh, float rw)
{
    long total = (long)B*C*ho*wo;
    long i = (long)blockIdx.x*TPB + threadIdx.x;
    if (i >= total) return;
    int x = (int)(i % wo); long t = i / wo;
    int y = (int)(t % ho); t /= ho;
    int c = (int)(t % C);  int b = (int)(t / C);
    float cy = (float)y*rh, cx = (float)x*rw;
    int y0 = (int)floorf(cy); if (y0 > hi-1) y0 = hi-1; if (y0 < 0) y0 = 0;
    int x0 = (int)floorf(cx); if (x0 > wi-1) x0 = wi-1; if (x0 < 0) x0 = 0;
    int y1 = y0+1; if (y1 > hi-1) y1 = hi-1;
    int x1 = x0+1; if (x1 > wi-1) x1 = wi-1;
    float fy = cy - (float)y0, fx = cx - (float)x0;
    const float* ib = in + (long)b*inb + (long)c*hi*wi;
    float a = ib[y0*wi+x0], b2 = ib[y0*wi+x1];
    float cc = ib[y1*wi+x0], d = ib[y1*wi+x1];
    float v = (a*(1.f-fy)+cc*fy)*(1.f-fx) + (b2*(1.f-fy)+d*fy)*fx;
    long oidx = (long)b*outb + (long)c*ho*wo + (long)y*wo + x;
    if (add) v += add[(long)b*addb + (long)c*ho*wo + (long)y*wo + x];
    out[oidx] = v;
}

// ---------------- ROI pooling -----------------------------------------------------
__global__ __launch_bounds__(TPB)
void roi_k(const float* __restrict__ z1, const float* __restrict__ xex,
           float* __restrict__ ze, float* __restrict__ sums,
           int ohw, int M, int C, int H, int W)
{
    int bj = blockIdx.x;
    int b = bj / M;
    int c = threadIdx.x;
    const float* bx = xex + (long)bj*4;
    int x_min = (int)(bx[0]/8.0f);
    int y_min = (int)(bx[1]/8.0f);
    int wdt   = (int)(bx[2]/8.0f);
    int hgt   = (int)(bx[3]/8.0f);
    int mx = hgt > wdt ? hgt : wdt;
    double scale = (double)mx / (double)ohw;
    int nh = (int)((double)hgt / scale); if (nh < 1) nh = 1;
    int nw = (int)((double)wdt / scale); if (nw < 1) nw = 1;
    if (nh > ohw) nh = ohw; if (nw > ohw) nw = ohw;
    int tp = (ohw - nh)/2, lp = (ohw - nw)/2;
    float rh = nh>1 ? (float)((double)hgt/(double)(nh-1)) : 0.f;
    float rw = nw>1 ? (float)((double)wdt/(double)(nw-1)) : 0.f;

    float* zeb = ze + ((long)bj*C + c)*ohw*ohw;
    for (int k=0;k<ohw*ohw;k++) zeb[k] = 0.f;

    const float* src = z1 + ((long)b*C + c)*H*W;
    float ssum = 0.f;
    for (int oy=0;oy<nh;oy++){
        float cy = (float)oy * rh;
        int y0 = (int)floorf(cy); if (y0 > hgt) y0 = hgt; if (y0 < 0) y0 = 0;
        int y1 = y0+1; if (y1 > hgt) y1 = hgt;
        float fy = cy - (float)y0;
        int gy0 = y_min + y0; if (gy0 > H-1) gy0 = H-1;
        int gy1 = y_min + y1; if (gy1 > H-1) gy1 = H-1;
        for (int ox=0;ox<nw;ox++){
            float cx = (float)ox * rw;
            int x0 = (int)floorf(cx); if (x0 > wdt) x0 = wdt; if (x0 < 0) x0 = 0;
            int x1 = x0+1; if (x1 > wdt) x1 = wdt;
            float fx = cx - (float)x0;
            int gx0 = x_min + x0; if (gx0 > W-1) gx0 = W-1;
            int gx1 = x_min + x1; if (gx1 > W-1) gx1 = W-1;
            float a = src[gy0*W+gx0], b2 = src[gy0*W+gx1];
            float cc = src[gy1*W+gx0], d = src[gy1*W+gx1];
            float v = (a*(1.f-fy)+cc*fy)*(1.f-fx) + (b2*(1.f-fy)+d*fy)*fx;
            zeb[(tp+oy)*ohw + lp+ox] = v;
            ssum += v;
        }
    }
    __shared__ float red[TPB];
    red[c] = ssum; __syncthreads();
    for (int s=TPB/2; s>0; s>>=1){
        if (c < s) red[c] += red[c+s];
        __syncthreads();
    }
    if (c==0) sums[bj] = red[0];
}

__global__ __launch_bounds__(TPB)
void norm_k(float* __restrict__ ze, const float* __restrict__ sums,
            int per_bj, long total, float* __restrict__ out2)
{
    long i = (long)blockIdx.x*TPB + threadIdx.x;
    if (i >= total) return;
    int bj = (int)(i / per_bj);
    float v = ze[i] / (1e-6f + sums[bj]);
    ze[i] = v;
    if (out2) out2[i] = v;
}

// ---------------- correlation v3: job-split, low register pressure ----------------
#define CRS 52
__global__ __launch_bounds__(TPB)
void corr3_k(const float* __restrict__ z1, const float* __restrict__ ze0,
             const float* __restrict__ ze1, const float* __restrict__ ze2,
             float* __restrict__ part)
{
    __shared__ __align__(16) float slds[44*CRS];
    __shared__ __align__(16) float wl[13*16];
    __shared__ float w1l[49];
    __shared__ float w0l[16];
    int tileI = blockIdx.x, job = blockIdx.y;
    int zz = blockIdx.z;
    int b = zz >> 5, cs = zz & 31;
    int x0 = (tileI&1)*32, y0 = (tileI>>1)*32;
    int tid = threadIdx.x, tx = tid&7, ty = tid>>3;
    int c0 = cs*(256/CORR_CS), c1 = c0 + (256/CORR_CS);

    float a[4][4];
#pragma unroll
    for (int f=0;f<4;f++)
#pragma unroll
        for (int p=0;p<4;p++) a[f][p]=0.f;

    for (int c=c0;c<c1;++c){
        __syncthreads();
        const float* ic = z1 + (((long)b*256 + c)<<12);
        for (int i=tid;i<44*44;i+=TPB){
            int row=i/44, col=i-row*44;
            int gy=y0-6+row, gx=x0-6+col;
            slds[row*CRS+col] = (gy>=0&&gy<64&&gx>=0&&gx<64)? ic[(gy<<6)+gx] : 0.f;
        }
        if (job<5){
            if (tid<169){
                wl[(tid/13)*16 + (tid%13)] = ze2[((long)(b*5+job)*256 + c)*169 + tid];
            }
        } else {
            if (tid<49) w1l[tid] = ze1[((long)(b*5)*256 + c)*49 + tid];
            else if (tid<65) w0l[tid-49] = ze0[((long)(b*5)*256 + c)*16 + (tid-49)];
        }
        __syncthreads();

        if (job<5){
            for (int r=0;r<13;r++){
                const float* srow = slds + (ty+r)*CRS + tx*4;
                float4 t0 = *(const float4*)(srow);
                float4 t1 = *(const float4*)(srow+4);
                float4 t2v = *(const float4*)(srow+8);
                float4 t3 = *(const float4*)(srow+12);
                float t[16];
                t[0]=t0.x; t[1]=t0.y; t[2]=t0.z; t[3]=t0.w;
                t[4]=t1.x; t[5]=t1.y; t[6]=t1.z; t[7]=t1.w;
                t[8]=t2v.x; t[9]=t2v.y; t[10]=t2v.z; t[11]=t2v.w;
                t[12]=t3.x; t[13]=t3.y; t[14]=t3.z; t[15]=t3.w;
                const float* wp0 = wl + r*16;
                const float* wp1 = wl + (12-r)*16;
                float4 A0=*(const float4*)(wp0), B0=*(const float4*)(wp0+4),
                       C0=*(const float4*)(wp0+8), D0=*(const float4*)(wp0+12);
                float4 A1=*(const float4*)(wp1), B1=*(const float4*)(wp1+4),
                       C1=*(const float4*)(wp1+8), D1=*(const float4*)(wp1+12);
                float w0r[13] = {A0.x,A0.y,A0.z,A0.w,B0.x,B0.y,B0.z,B0.w,C0.x,C0.y,C0.z,C0.w,D0.x};
                float w1r[13] = {A1.x,A1.y,A1.z,A1.w,B1.x,B1.y,B1.z,B1.w,C1.x,C1.y,C1.z,C1.w,D1.x};
#pragma unroll
                for (int k=0;k<13;k++){
                    float wa = w0r[k], wb = w0r[12-k];
                    float wc = w1r[k], wd = w1r[12-k];
#pragma unroll
                    for (int p=0;p<4;p++){
                        float xv = t[p+k];
                        a[0][p] = fmaf(xv, wa, a[0][p]);
                        a[1][p] = fmaf(xv, wb, a[1][p]);
                        a[2][p] = fmaf(xv, wc, a[2][p]);
                        a[3][p] = fmaf(xv, wd, a[3][p]);
                    }
                }
            }
        } else {
#pragma unroll
            for (int i4=0;i4<4;i4++){
                const float* sr = slds + (ty+4+i4)*CRS + tx*4 + 4;
                float t7[7];
#pragma unroll
                for (int q=0;q<7;q++) t7[q]=sr[q];
#pragma unroll
                for (int t=0;t<4;t++){
                    float wv = w0l[i4*4+t];
#pragma unroll
                    for (int p=0;p<4;p++) a[0][p] = fmaf(t7[p+t], wv, a[0][p]);
                }
            }
#pragma unroll
            for (int i7=0;i7<7;i7++){
                const float* sr = slds + (ty+3+i7)*CRS + tx*4 + 3;
                float t10[10];
#pragma unroll
                for (int q=0;q<10;q++) t10[q]=sr[q];
#pragma unroll
                for (int t=0;t<7;t++){
                    float wv = w1l[i7*7+t];
#pragma unroll
                    for (int p=0;p<4;p++) a[1][p] = fmaf(t10[p+t], wv, a[1][p]);
                }
            }
        }
    }

    int y = y0+ty, x = x0+tx*4;
    long base = (long)(b*CORR_CS+cs)*22;
    if (job<5){
#pragma unroll
        for (int f=0;f<4;f++){
            int oc = 2 + f*5 + job;
            *(float4*)(part + ((base+oc)<<12) + (y<<6) + x) =
                make_float4(a[f][0],a[f][1],a[f][2],a[f][3]);
        }
    } else {
        *(float4*)(part + ((base+0)<<12) + (y<<6) + x) = make_float4(a[0][0],a[0][1],a[0][2],a[0][3]);
        *(float4*)(part + ((base+1)<<12) + (y<<6) + x) = make_float4(a[1][0],a[1][1],a[1][2],a[1][3]);
    }
}

__global__ __launch_bounds__(TPB)
void corrred_k(const float* __restrict__ part, float* __restrict__ cm)
{
    long total = (long)2*22*4096;
    long i = (long)blockIdx.x*TPB + threadIdx.x;
    if (i>=total) return;
    int px = (int)(i & 4095); long t = i >> 12;
    int oc = (int)(t % 22); int b = (int)(t / 22);
    float s = 0.f;
    for (int cs=0;cs<CORR_CS;cs++)
        s += part[(((long)(b*CORR_CS+cs)*22 + oc)<<12) + px];
    cm[((long)(b*22+oc)<<12) + px] = s;
}

__global__ __launch_bounds__(TPB)
void atten_k(const float* __restrict__ cmap, float* __restrict__ att, int B, int HW)
{
    int i = blockIdx.x*TPB + threadIdx.x;
    if (i >= B*HW) return;
    int b = i/HW, p = i%HW;
    float s = 0.f;
    for (int m=0;m<22;m++) s += cmap[((long)(b*22+m))*HW + p];
    att[i] = s * (1.f/60.f);
}

// h has only the 278 live channels: [cmap 22][z1*atten 256]
__global__ __launch_bounds__(TPB)
void buildh_k(const float* __restrict__ cmap, const float* __restrict__ z1,
              const float* __restrict__ att, float* __restrict__ h, int B, int HW)
{
    long total = (long)B*278*HW;
    long i = (long)blockIdx.x*TPB + threadIdx.x;
    if (i >= total) return;
    int p = (int)(i % HW); long t = i / HW;
    int ch = (int)(t % 278); int b = (int)(t / 278);
    float v;
    if (ch < 22) v = cmap[((long)(b*22+ch))*HW + p];
    else         v = z1[((long)b*256 + (ch-22))*HW + p] * att[b*HW + p];
    h[i] = v;
}

static inline float acr(int nin, int nout){
    return (float)(((double)(nin-1))/(double)(nout-1));
}

extern "C" void kernel_launch(void* const* d_in, const int* in_sizes, int n_in,
                              void* d_out_v, int out_size, void* d_ws, size_t ws_size,
                              hipStream_t stream)
{
    const float* x0  = (const float*)d_in[0];
    const float* x1  = (const float*)d_in[1];
    const float* x2  = (const float*)d_in[2];
    const float* x3  = (const float*)d_in[3];
    const float* xex = (const float*)d_in[4];
    const float* c1w0=(const float*)d_in[5];  const float* c1b0=(const float*)d_in[6];
    const float* c1w1=(const float*)d_in[7];  const float* c1b1=(const float*)d_in[8];
    const float* c1w2=(const float*)d_in[9];  const float* c1b2=(const float*)d_in[10];
    const float* smw =(const float*)d_in[11]; const float* smb =(const float*)d_in[12];
    const float* fw  =(const float*)d_in[13];
    const float* bng =(const float*)d_in[14]; const float* bnb =(const float*)d_in[15];
    const float* lw1 =(const float*)d_in[16]; const float* lb1 =(const float*)d_in[17];
    const float* lw2 =(const float*)d_in[18]; const float* lb2 =(const float*)d_in[19];
    const float* lw3 =(const float*)d_in[20]; const float* lb3 =(const float*)d_in[21];
    const float* ow1 =(const float*)d_in[22]; const float* ob1 =(const float*)d_in[23];
    const float* ow2 =(const float*)d_in[24]; const float* ob2 =(const float*)d_in[25];
    const float* ow3 =(const float*)d_in[26]; const float* ob3 =(const float*)d_in[27];
    float* dout = (float*)d_out_v;
    float* ws   = (float*)d_ws;

    const int B=2, HW=4096;

    float* f1  = ws;               // 2*256*1024
    float* f2  = f1  + 524288;     // 2*256*256
    float* f3  = f2  + 131072;     // 2*256*64
    float* P1  = f3  + 32768;      // 2*256*4096
    float* P2  = P1  + 2097152;    // 2*256*1024
    float* P3  = P2  + 524288;     // 2*256*256
    float* S2  = P3  + 131072;     // 2*256*1024
    float* S3  = S2  + 524288;     // 2*256*256
    float* CC  = S3  + 131072;     // 2*1024*4096
    float* Z1  = CC  + 8388608;    // 2*256*4096
    float* ZE0 = Z1  + 2097152;    // 2*5*256*16
    float* ZE1 = ZE0 + 40960;      // 2*5*256*49
    float* ZE2 = ZE1 + 125440;     // 2*5*256*169
    float* SUM = ZE2 + 432640;     // 32
    float* CM  = SUM + 32;         // 2*22*4096
    float* Hb  = CM  + 180224;     // 2*278*4096 used
    float* HB1 = Hb  + 2588672;
    float* HB2 = HB1 + 524288;
    float* O164= HB2 + 524288;
    float* OB1 = O164+ 8192;
    float* OB2 = OB1 + 524288;
    float* OFF = OB2 + 524288;
    float* PBF = Hb;               // partial buffer #1 (dead before buildh)
    float* PBC = CC;               // partial buffer #2 (dead after fuse conv)

    float* out1_dst = dout;               // (2,1,512,512)
    float* off_dst  = dout + 524288;      // (2,2,512,512)
    float* att_dst  = dout + 1572864;     // (2,1,64,64)
    float* ze_dst   = dout + 1581056;     // (2,5,256,13,13)

    // 1) FPN lateral 1x1 convs (channel-split, partials in PBF)
    conv_k<1><<<dim3(4,32,B*2), TPB, 0, stream>>>(x1, 512*1024, PBF, 0, c1w0, nullptr, nullptr, 512,256,32,32, M_BIAS, 2);
    convred_k<<<(524288+TPB-1)/TPB, TPB, 0, stream>>>(PBF, f1, 256*1024, c1b0, nullptr, 256, 1024, 2, M_BIAS);
    conv_k<1><<<dim3(1,32,B*8), TPB, 0, stream>>>(x2, 1024*256, PBF, 0, c1w1, nullptr, nullptr, 1024,256,16,16, M_BIAS, 8);
    convred_k<<<(131072+TPB-1)/TPB, TPB, 0, stream>>>(PBF, f2, 256*256, c1b1, nullptr, 256, 256, 8, M_BIAS);
    conv_k<1><<<dim3(1,32,B*8), TPB, 0, stream>>>(x3, 2048*64, PBF, 0, c1w2, nullptr, nullptr, 2048,256,8,8, M_BIAS, 8);
    convred_k<<<(32768+TPB-1)/TPB, TPB, 0, stream>>>(PBF, f3, 256*64, c1b2, nullptr, 256, 64, 8, M_BIAS);

    // 2) top-down resize + add
    resize_k<<<(131072+TPB-1)/TPB, TPB, 0, stream>>>(f3, 256*64, 8,8,   P3, 256*256, 16,16, f2, 256*256, 256, B, acr(8,16), acr(8,16));
    resize_k<<<(524288+TPB-1)/TPB, TPB, 0, stream>>>(f2, 256*256, 16,16, P2, 256*1024, 32,32, f1, 256*1024, 256, B, acr(16,32), acr(16,32));
    resize_k<<<(2097152+TPB-1)/TPB, TPB, 0, stream>>>(f1, 256*1024, 32,32, P1, 256*4096, 64,64, x0, 256*4096, 256, B, acr(32,64), acr(32,64));

    // 3) smooth convs (@64 via conv3w8, partials CS=2 -> CC ch0..255)
    conv3w8<<<dim3(4,32,B*2), 128, 0, stream>>>(P1, 256*4096, PBF, smw, 256, 256, 2, 256, 0);
    convred_k<<<(2097152+TPB-1)/TPB, TPB, 0, stream>>>(PBF, CC, 1024*4096, smb, nullptr, 256, 4096, 2, M_BIAS);
    conv_k<3><<<dim3(4,32,B*2), TPB, 0, stream>>>(P2, 256*1024, PBF, 0, smw, nullptr, nullptr, 256,256,32,32, M_BIAS, 2);
    convred_k<<<(524288+TPB-1)/TPB, TPB, 0, stream>>>(PBF, S2, 256*1024, smb, nullptr, 256, 1024, 2, M_BIAS);
    conv_k<3><<<dim3(1,32,B*4), TPB, 0, stream>>>(P3, 256*256, PBF, 0, smw, nullptr, nullptr, 256,256,16,16, M_BIAS, 4);
    convred_k<<<(131072+TPB-1)/TPB, TPB, 0, stream>>>(PBF, S3, 256*256, smb, nullptr, 256, 256, 4, M_BIAS);

    // 4) resize into concat slices
    resize_k<<<(2097152+TPB-1)/TPB, TPB, 0, stream>>>(S2, 256*1024, 32,32, CC+256*4096, 1024*4096, 64,64, nullptr,0, 256, B, acr(32,64), acr(32,64));
    resize_k<<<(2097152+TPB-1)/TPB, TPB, 0, stream>>>(S3, 256*256,  16,16, CC+512*4096, 1024*4096, 64,64, nullptr,0, 256, B, acr(16,64), acr(16,64));
    resize_k<<<(2097152+TPB-1)/TPB, TPB, 0, stream>>>(f3, 256*64,   8,8,   CC+768*4096, 1024*4096, 64,64, nullptr,0, 256, B, acr(8,64),  acr(8,64));

    // 5) fuse conv + bn + relu -> Z1 (conv3w8 CS=2, partials in PBF)
    conv3w8<<<dim3(4,32,B*2), 128, 0, stream>>>(CC, 1024*4096, PBF, fw, 1024, 256, 2, 1024, 0);
    convred_k<<<(2097152+TPB-1)/TPB, TPB, 0, stream>>>(PBF, Z1, 256*4096, bng, bnb, 256, 4096, 2, M_BN_RELU);

    // 6) ROI pooling + normalize
    roi_k<<<B*5, TPB, 0, stream>>>(Z1, xex, ZE0, SUM+0,  4,  5, 256, 64, 64);
    roi_k<<<B*5, TPB, 0, stream>>>(Z1, xex, ZE1, SUM+10, 7,  5, 256, 64, 64);
    roi_k<<<B*5, TPB, 0, stream>>>(Z1, xex, ZE2, SUM+20, 13, 5, 256, 64, 64);
    norm_k<<<(40960+TPB-1)/TPB,  TPB, 0, stream>>>(ZE0, SUM+0,  256*16,  40960,  nullptr);
    norm_k<<<(125440+TPB-1)/TPB, TPB, 0, stream>>>(ZE1, SUM+10, 256*49,  125440, nullptr);
    norm_k<<<(432640+TPB-1)/TPB, TPB, 0, stream>>>(ZE2, SUM+20, 256*169, 432640, ze_dst);

    // 7) correlation (job-split), partials in PBC
    corr3_k<<<dim3(4,6,B*CORR_CS), TPB, 0, stream>>>(Z1, ZE0, ZE1, ZE2, PBC);
    corrred_k<<<(180224+TPB-1)/TPB, TPB, 0, stream>>>(PBC, CM);

    // 8) atten
    atten_k<<<(B*HW+TPB-1)/TPB, TPB, 0, stream>>>(CM, att_dst, B, HW);

    // 9) build h (278 live channels)
    buildh_k<<<((long)B*278*HW+TPB-1)/TPB, TPB, 0, stream>>>(CM, Z1, att_dst, Hb, B, HW);

    // 10) ll chain (ll1 via conv3w8 CS=8)
    conv3w8<<<dim3(4,8,B*8), 128, 0, stream>>>(Hb, 278*4096, PBC, lw1, 278, 64, 8, 316, 1);
    convred_k<<<(524288+TPB-1)/TPB, TPB, 0, stream>>>(PBC, HB1, 64*4096, lb1, nullptr, 64, 4096, 8, M_BIAS_RELU);
    conv3_64<<<dim3(2,16,B*8), TPB, 0, stream>>>(HB1, 64*4096, PBC, 0, lw2, nullptr, nullptr, 64,64, M_BIAS_RELU, 8, 64, 0);
    convred_k<<<(524288+TPB-1)/TPB, TPB, 0, stream>>>(PBC, HB2, 64*4096, lb2, nullptr, 64, 4096, 8, M_BIAS_RELU);
    conv_k<1><<<dim3(16,1,B), TPB, 0, stream>>>(HB2, 64*4096, O164, 1*4096, lw3, lb3, nullptr, 64,1,64,64, M_BIAS_RELU, 1);

    // 11) offset chain (of1 via conv3w8 CS=8)
    conv3w8<<<dim3(4,8,B*8), 128, 0, stream>>>(Z1, 256*4096, PBC, ow1, 256, 64, 8, 256, 0);
    convred_k<<<(524288+TPB-1)/TPB, TPB, 0, stream>>>(PBC, OB1, 64*4096, ob1, nullptr, 64, 4096, 8, M_BIAS_RELU);
    conv3_64<<<dim3(2,16,B*8), TPB, 0, stream>>>(OB1, 64*4096, PBC, 0, ow2, nullptr, nullptr, 64,64, M_BIAS_RELU, 8, 64, 0);
    convred_k<<<(524288+TPB-1)/TPB, TPB, 0, stream>>>(PBC, OB2, 64*4096, ob2, nullptr, 64, 4096, 8, M_BIAS_RELU);
    conv_k<1><<<dim3(16,1,B), TPB, 0, stream>>>(OB2, 64*4096, OFF, 2*4096, ow3, ob3, nullptr, 64,2,64,64, M_SIGAFF, 1);

    // 12) final upsamples
    resize_k<<<(524288+TPB-1)/TPB,  TPB, 0, stream>>>(O164, 4096, 64,64, out1_dst, 262144, 512,512, nullptr,0, 1, B, acr(64,512), acr(64,512));
    resize_k<<<(1048576+TPB-1)/TPB, TPB, 0, stream>>>(OFF,  8192, 64,64, off_dst,  524288, 512,512, nullptr,0, 2, B, acr(64,512), acr(64,512));
}

// Round 12
// 2831.238 us; speedup vs baseline: 1.0957x; 1.0957x over previous
//
#include <hip/hip_runtime.h>
#include <math.h>

#define TPB 256
#define TILE 16
#define OCB 8
#define CORR_CS 32

enum { M_BIAS=0, M_BIAS_RELU=1, M_BN_RELU=2, M_SIGAFF=3 };

// ---------------- generic direct conv (small layers), optional channel-split -----
template<int K>
__global__ __launch_bounds__(TPB)
void conv_k(const float* __restrict__ in, long inb,
            float* __restrict__ out, long outb,
            const float* __restrict__ w,
            const float* __restrict__ a1, const float* __restrict__ a2,
            int Cin, int Cout, int H, int W, int mode, int CS)
{
    constexpr int PAD = K/2;
    constexpr int S = TILE + K - 1;
    __shared__ float tile[S*S];
    __shared__ float wl[OCB*K*K];
    int tilesX = (W + TILE-1)/TILE;
    int tY = blockIdx.x / tilesX, tX = blockIdx.x % tilesX;
    int oc0 = blockIdx.y * OCB;
    int zz = blockIdx.z;
    int cs = zz % CS, b = zz / CS;
    int c0 = (cs*Cin)/CS, c1 = ((cs+1)*Cin)/CS;
    int tid = threadIdx.x;
    int ty = tid / TILE, tx = tid % TILE;
    int y = tY*TILE+ty, x = tX*TILE+tx;
    int oy0 = tY*TILE - PAD, ox0 = tX*TILE - PAD;
    int ocmax = Cout - oc0; if (ocmax > OCB) ocmax = OCB;
    float acc[OCB];
#pragma unroll
    for (int o=0;o<OCB;o++) acc[o]=0.f;
    const float* inp = in + (long)b*inb;
    const int HW = H*W;

    for (int c=c0;c<c1;c++){
        __syncthreads();
        const float* ic = inp + (long)c*HW;
        for (int idx=tid; idx<S*S; idx+=TPB){
            int sy = oy0 + idx/S, sx = ox0 + idx%S;
            tile[idx] = (sy>=0 && sy<H && sx>=0 && sx<W) ? ic[sy*W+sx] : 0.f;
        }
        if (tid < ocmax*(K*K)){
            int o = tid/(K*K), k = tid - o*(K*K);
            wl[o*(K*K)+k] = w[((long)(oc0+o)*Cin + c)*(K*K) + k];
        }
        __syncthreads();
        for (int k=0;k<K*K;k++){
            float xv = tile[(ty + k/K)*S + tx + k%K];
            for (int o=0;o<ocmax;o++)
                acc[o] = fmaf(xv, wl[o*(K*K)+k], acc[o]);
        }
    }

    if (y<H && x<W){
        if (CS==1){
            for (int o=0;o<ocmax;o++){
                int oc = oc0+o;
                float v = acc[o];
                if (mode==M_BIAS) { v += a1[oc]; }
                else if (mode==M_BIAS_RELU) { v += a1[oc]; v = fmaxf(v,0.f); }
                else if (mode==M_BN_RELU) { v = v / sqrtf(1.0f+1e-5f) * a1[oc] + a2[oc]; v = fmaxf(v,0.f); }
                else { v += a1[oc]; float s = 1.f/(1.f+expf(-v)); v = (8.f*s - 4.f)*8.f; }
                out[(long)b*outb + (long)oc*HW + (long)y*W + x] = v;
            }
        } else {
            for (int o=0;o<ocmax;o++)
                out[(((long)(b*CS+cs)*Cout + (oc0+o))*(long)HW) + (long)y*W + x] = acc[o];
        }
    }
}

// ---------------- specialized 3x3 conv for 64x64 planes (4 oc/thread) ------------
#define C3S 76
__global__ __launch_bounds__(TPB)
void conv3_64(const float* __restrict__ in, long inb,
              float* __restrict__ out, long outb,
              const float* __restrict__ w,
              const float* __restrict__ a1, const float* __restrict__ a2,
              int Cin, int Cout, int mode, int CS, int wCin, int wskip)
{
    __shared__ __align__(16) float slds[34*C3S];
    __shared__ __align__(16) float wlds[9*4];
    int ytile = blockIdx.x;
    int oc0 = blockIdx.y*4;
    int zz = blockIdx.z;
    int cs = zz % CS, b = zz / CS;
    int c0 = (cs*Cin)/CS, c1 = ((cs+1)*Cin)/CS;
    int tid = threadIdx.x;
    int tx = tid >> 5, ty = tid & 31;
    int y0 = ytile*32;
    const long wstr = (long)wCin*9;

    for (int i=tid;i<34*12;i+=TPB){
        int row=i/12, j=i-row*12;
        int col = (j<4)? j : 64+j;
        slds[row*C3S+col] = 0.f;
    }

    float acc[8][4];
#pragma unroll
    for (int p=0;p<8;p++)
#pragma unroll
        for (int o=0;o<4;o++) acc[p][o]=0.f;

    for (int c=c0;c<c1;++c){
        __syncthreads();
        const float* ic = in + (long)b*inb + ((long)c<<12);
        for (int i=tid;i<544;i+=TPB){
            int row=i>>4, q=i&15;
            int gy = y0-1+row;
            float4 v = make_float4(0.f,0.f,0.f,0.f);
            if (gy>=0 && gy<64) v = *(const float4*)(ic + (gy<<6) + q*4);
            *(float4*)(slds + row*C3S + 4 + q*4) = v;
        }
        int cw = (wskip && c>=22) ? c+38 : c;
        if (tid<36){
            int o=tid/9, k=tid-o*9;
            wlds[k*4+o] = w[(long)(oc0+o)*wstr + (long)cw*9 + k];
        }
        __syncthreads();

#pragma unroll
        for (int r=0;r<3;r++){
            const float* srow = slds + (ty+r)*C3S + tx*8;
            float4 r0 = *(const float4*)(srow);
            float4 r1 = *(const float4*)(srow+4);
            float4 r2 = *(const float4*)(srow+8);
            float4 r3 = *(const float4*)(srow+12);
            float t[10];
            t[0]=r0.w;
            t[1]=r1.x; t[2]=r1.y; t[3]=r1.z; t[4]=r1.w;
            t[5]=r2.x; t[6]=r2.y; t[7]=r2.z; t[8]=r2.w;
            t[9]=r3.x;
#pragma unroll
            for (int k=0;k<3;k++){
                float4 w4 = *(const float4*)(wlds + (r*3+k)*4);
#pragma unroll
                for (int p=0;p<8;p++){
                    acc[p][0] = fmaf(t[p+k], w4.x, acc[p][0]);
                    acc[p][1] = fmaf(t[p+k], w4.y, acc[p][1]);
                    acc[p][2] = fmaf(t[p+k], w4.z, acc[p][2]);
                    acc[p][3] = fmaf(t[p+k], w4.w, acc[p][3]);
                }
            }
        }
    }

    int y = y0+ty, x = tx*8;
    if (CS==1){
#pragma unroll
        for (int o=0;o<4;o++){
            int oc = oc0+o;
            float bb=0.f, gg=1.f;
            if (mode==M_BN_RELU){ gg=a1[oc]; bb=a2[oc]; }
            else { bb=a1[oc]; }
            float v[8];
#pragma unroll
            for (int p=0;p<8;p++){
                float u = acc[p][o];
                if (mode==M_BIAS) u += bb;
                else if (mode==M_BIAS_RELU){ u += bb; u = fmaxf(u,0.f); }
                else if (mode==M_BN_RELU){ u = u / sqrtf(1.0f+1e-5f) * gg + bb; u = fmaxf(u,0.f); }
                v[p] = u;
            }
            float* op = out + (long)b*outb + ((long)oc<<12) + (y<<6) + x;
            *(float4*)(op)   = make_float4(v[0],v[1],v[2],v[3]);
            *(float4*)(op+4) = make_float4(v[4],v[5],v[6],v[7]);
        }
    } else {
#pragma unroll
        for (int o=0;o<4;o++){
            float* op = out + (((long)(b*CS+cs)*Cout + (oc0+o))<<12) + (y<<6) + x;
            *(float4*)(op)   = make_float4(acc[0][o],acc[1][o],acc[2][o],acc[3][o]);
            *(float4*)(op+4) = make_float4(acc[4][o],acc[5][o],acc[6][o],acc[7][o]);
        }
    }
}

// ---------------- 3x3 conv @64x64, 8 oc/thread, register-prefetch pipeline -------
// 128 thr = 8tx * 16ty; 16-row tiles; pad=4 (aligned b128 stage writes + reads).
// Per channel: prefetch c+1 into regs, then compute c -> global latency hidden.
__global__ __launch_bounds__(128)
void conv3p(const float* __restrict__ in, long inb,
            float* __restrict__ out,
            const float* __restrict__ w,
            int Cin, int Cout, int CS, int wCin, int wskip)
{
    __shared__ __align__(16) float slds[18*C3S];
    __shared__ __align__(16) float wlds[9*8];
    int ytile = blockIdx.x;            // 0..3
    int oc0 = blockIdx.y*8;
    int zz = blockIdx.z;
    int cs = zz % CS, b = zz / CS;
    int c0 = (cs*Cin)/CS, c1 = ((cs+1)*Cin)/CS;
    int tid = threadIdx.x;
    int tx = tid & 7, ty = tid >> 3;   // ty 0..15
    int y0 = ytile*16;
    const long wstr = (long)wCin*9;

    // zero pads: cols(word) 0..3 and 68..75, rows 0..17
    for (int i=tid;i<18*12;i+=128){
        int row=i/12, j=i-row*12;
        int col = (j<4)? j : 64+j;
        slds[row*C3S+col] = 0.f;
    }

    float acc[8][8];
#pragma unroll
    for (int p=0;p<8;p++)
#pragma unroll
        for (int o=0;o<8;o++) acc[p][o]=0.f;

    int r0i = tid>>4, r1i = r0i+8, r2i = r0i+16;   // staged rows per thread
    int q = tid&15;
    int wo = tid/9, wk = tid - wo*9;               // weight slot (tid<72)

    float4 pv0, pv1, pv2;
    float pw = 0.f;

    // prologue prefetch (c0)
    {
        const float* ic = in + (long)b*inb + ((long)c0<<12);
        int gy;
        gy = y0-1+r0i; pv0 = (gy>=0&&gy<64)? *(const float4*)(ic+(gy<<6)+q*4) : make_float4(0.f,0.f,0.f,0.f);
        gy = y0-1+r1i; pv1 = (gy>=0&&gy<64)? *(const float4*)(ic+(gy<<6)+q*4) : make_float4(0.f,0.f,0.f,0.f);
        if (tid<32){ gy = y0-1+r2i; pv2 = (gy>=0&&gy<64)? *(const float4*)(ic+(gy<<6)+q*4) : make_float4(0.f,0.f,0.f,0.f); }
        if (tid<72){ int cw=(wskip&&c0>=22)?c0+38:c0; pw = w[(long)(oc0+wo)*wstr + (long)cw*9 + wk]; }
    }

    for (int c=c0;c<c1;++c){
        __syncthreads();   // all waves finished reading previous channel
        *(float4*)(slds + r0i*C3S + 4 + q*4) = pv0;
        *(float4*)(slds + r1i*C3S + 4 + q*4) = pv1;
        if (tid<32) *(float4*)(slds + r2i*C3S + 4 + q*4) = pv2;
        if (tid<72) wlds[wk*8+wo] = pw;
        __syncthreads();

        if (c+1 < c1){
            const float* ic = in + (long)b*inb + ((long)(c+1)<<12);
            int gy;
            gy = y0-1+r0i; pv0 = (gy>=0&&gy<64)? *(const float4*)(ic+(gy<<6)+q*4) : make_float4(0.f,0.f,0.f,0.f);
            gy = y0-1+r1i; pv1 = (gy>=0&&gy<64)? *(const float4*)(ic+(gy<<6)+q*4) : make_float4(0.f,0.f,0.f,0.f);
            if (tid<32){ gy = y0-1+r2i; pv2 = (gy>=0&&gy<64)? *(const float4*)(ic+(gy<<6)+q*4) : make_float4(0.f,0.f,0.f,0.f); }
            if (tid<72){ int cn=c+1; int cw=(wskip&&cn>=22)?cn+38:cn; pw = w[(long)(oc0+wo)*wstr + (long)cw*9 + wk]; }
        }

#pragma unroll
        for (int r=0;r<3;r++){
            const float* srow = slds + (ty+r)*C3S + tx*8;
            float4 r0 = *(const float4*)(srow);
            float4 r1 = *(const float4*)(srow+4);
            float4 r2 = *(const float4*)(srow+8);
            float4 r3 = *(const float4*)(srow+12);
            float t[10];
            t[0]=r0.w;
            t[1]=r1.x; t[2]=r1.y; t[3]=r1.z; t[4]=r1.w;
            t[5]=r2.x; t[6]=r2.y; t[7]=r2.z; t[8]=r2.w;
            t[9]=r3.x;
#pragma unroll
            for (int k=0;k<3;k++){
                float4 wa = *(const float4*)(wlds + (r*3+k)*8);
                float4 wb = *(const float4*)(wlds + (r*3+k)*8 + 4);
#pragma unroll
                for (int p=0;p<8;p++){
                    float xv = t[p+k];
                    acc[p][0] = fmaf(xv, wa.x, acc[p][0]);
                    acc[p][1] = fmaf(xv, wa.y, acc[p][1]);
                    acc[p][2] = fmaf(xv, wa.z, acc[p][2]);
                    acc[p][3] = fmaf(xv, wa.w, acc[p][3]);
                    acc[p][4] = fmaf(xv, wb.x, acc[p][4]);
                    acc[p][5] = fmaf(xv, wb.y, acc[p][5]);
                    acc[p][6] = fmaf(xv, wb.z, acc[p][6]);
                    acc[p][7] = fmaf(xv, wb.w, acc[p][7]);
                }
            }
        }
    }

    int y = y0+ty, x = tx*8;
#pragma unroll
    for (int o=0;o<8;o++){
        float* op = out + (((long)(b*CS+cs)*Cout + (oc0+o))<<12) + (y<<6) + x;
        *(float4*)(op)   = make_float4(acc[0][o],acc[1][o],acc[2][o],acc[3][o]);
        *(float4*)(op+4) = make_float4(acc[4][o],acc[5][o],acc[6][o],acc[7][o]);
    }
}

// ---------------- partial-sum reduce + bias/bn/act -------------------------------
__global__ __launch_bounds__(TPB)
void convred_k(const float* __restrict__ part, float* __restrict__ out, long outb,
               const float* __restrict__ a1, const float* __restrict__ a2,
               int Cout, int HW, int CS, int mode)
{
    long total = (long)2*Cout*HW;
    long i = (long)blockIdx.x*TPB + threadIdx.x;
    if (i>=total) return;
    int px = (int)(i % HW); long t = i / HW;
    int oc = (int)(t % Cout); int b = (int)(t / Cout);
    float s = 0.f;
    for (int cs=0;cs<CS;cs++) s += part[(((long)(b*CS+cs)*Cout + oc)*(long)HW) + px];
    if (mode==M_BIAS) s += a1[oc];
    else if (mode==M_BIAS_RELU){ s += a1[oc]; s = fmaxf(s,0.f); }
    else { s = s / sqrtf(1.0f+1e-5f) * a1[oc] + a2[oc]; s = fmaxf(s,0.f); }
    out[(long)b*outb + (long)oc*HW + px] = s;
}

// ---------------- bilinear resize, align_corners=True, optional add ---------------
__global__ __launch_bounds__(TPB)
void resize_k(const float* __restrict__ in, long inb, int hi, int wi,
              float* __restrict__ out, long outb, int ho, int wo,
              const float* __restrict__ add, long addb,
              int C, int B, float rh, float rw)
{
    long total = (long)B*C*ho*wo;
    long i = (long)blockIdx.x*TPB + threadIdx.x;
    if (i >= total) return;
    int x = (int)(i % wo); long t = i / wo;
    int y = (int)(t % ho); t /= ho;
    int c = (int)(t % C);  int b = (int)(t / C);
    float cy = (float)y*rh, cx = (float)x*rw;
    int y0 = (int)floorf(cy); if (y0 > hi-1) y0 = hi-1; if (y0 < 0) y0 = 0;
    int x0 = (int)floorf(cx); if (x0 > wi-1) x0 = wi-1; if (x0 < 0) x0 = 0;
    int y1 = y0+1; if (y1 > hi-1) y1 = hi-1;
    int x1 = x0+1; if (x1 > wi-1) x1 = wi-1;
    float fy = cy - (float)y0, fx = cx - (float)x0;
    const float* ib = in + (long)b*inb + (long)c*hi*wi;
    float a = ib[y0*wi+x0], b2 = ib[y0*wi+x1];
    float cc = ib[y1*wi+x0], d = ib[y1*wi+x1];
    float v = (a*(1.f-fy)+cc*fy)*(1.f-fx) + (b2*(1.f-fy)+d*fy)*fx;
    long oidx = (long)b*outb + (long)c*ho*wo + (long)y*wo + x;
    if (add) v += add[(long)b*addb + (long)c*ho*wo + (long)y*wo + x];
    out[oidx] = v;
}

// ---------------- ROI pooling -----------------------------------------------------
__global__ __launch_bounds__(TPB)
void roi_k(const float* __restrict__ z1, const float* __restrict__ xex,
           float* __restrict__ ze, float* __restrict__ sums,
           int ohw, int M, int C, int H, int W)
{
    int bj = blockIdx.x;
    int b = bj / M;
    int c = threadIdx.x;
    const float* bx = xex + (long)bj*4;
    int x_min = (int)(bx[0]/8.0f);
    int y_min = (int)(bx[1]/8.0f);
    int wdt   = (int)(bx[2]/8.0f);
    int hgt   = (int)(bx[3]/8.0f);
    int mx = hgt > wdt ? hgt : wdt;
    double scale = (double)mx / (double)ohw;
    int nh = (int)((double)hgt / scale); if (nh < 1) nh = 1;
    int nw = (int)((double)wdt / scale); if (nw < 1) nw = 1;
    if (nh > ohw) nh = ohw; if (nw > ohw) nw = ohw;
    int tp = (ohw - nh)/2, lp = (ohw - nw)/2;
    float rh = nh>1 ? (float)((double)hgt/(double)(nh-1)) : 0.f;
    float rw = nw>1 ? (float)((double)wdt/(double)(nw-1)) : 0.f;

    float* zeb = ze + ((long)bj*C + c)*ohw*ohw;
    for (int k=0;k<ohw*ohw;k++) zeb[k] = 0.f;

    const float* src = z1 + ((long)b*C + c)*H*W;
    float ssum = 0.f;
    for (int oy=0;oy<nh;oy++){
        float cy = (float)oy * rh;
        int y0 = (int)floorf(cy); if (y0 > hgt) y0 = hgt; if (y0 < 0) y0 = 0;
        int y1 = y0+1; if (y1 > hgt) y1 = hgt;
        float fy = cy - (float)y0;
        int gy0 = y_min + y0; if (gy0 > H-1) gy0 = H-1;
        int gy1 = y_min + y1; if (gy1 > H-1) gy1 = H-1;
        for (int ox=0;ox<nw;ox++){
            float cx = (float)ox * rw;
            int x0 = (int)floorf(cx); if (x0 > wdt) x0 = wdt; if (x0 < 0) x0 = 0;
            int x1 = x0+1; if (x1 > wdt) x1 = wdt;
            float fx = cx - (float)x0;
            int gx0 = x_min + x0; if (gx0 > W-1) gx0 = W-1;
            int gx1 = x_min + x1; if (gx1 > W-1) gx1 = W-1;
            float a = src[gy0*W+gx0], b2 = src[gy0*W+gx1];
            float cc = src[gy1*W+gx0], d = src[gy1*W+gx1];
            float v = (a*(1.f-fy)+cc*fy)*(1.f-fx) + (b2*(1.f-fy)+d*fy)*fx;
            zeb[(tp+oy)*ohw + lp+ox] = v;
            ssum += v;
        }
    }
    __shared__ float red[TPB];
    red[c] = ssum; __syncthreads();
    for (int s=TPB/2; s>0; s>>=1){
        if (c < s) red[c] += red[c+s];
        __syncthreads();
    }
    if (c==0) sums[bj] = red[0];
}

__global__ __launch_bounds__(TPB)
void norm_k(float* __restrict__ ze, const float* __restrict__ sums,
            int per_bj, long total, float* __restrict__ out2)
{
    long i = (long)blockIdx.x*TPB + threadIdx.x;
    if (i >= total) return;
    int bj = (int)(i / per_bj);
    float v = ze[i] / (1e-6f + sums[bj]);
    ze[i] = v;
    if (out2) out2[i] = v;
}

// ---------------- correlation v3: job-split, low register pressure ----------------
#define CRS 52
__global__ __launch_bounds__(TPB)
void corr3_k(const float* __restrict__ z1, const float* __restrict__ ze0,
             const float* __restrict__ ze1, const float* __restrict__ ze2,
             float* __restrict__ part)
{
    __shared__ __align__(16) float slds[44*CRS];
    __shared__ __align__(16) float wl[13*16];
    __shared__ float w1l[49];
    __shared__ float w0l[16];
    int tileI = blockIdx.x, job = blockIdx.y;
    int zz = blockIdx.z;
    int b = zz >> 5, cs = zz & 31;
    int x0 = (tileI&1)*32, y0 = (tileI>>1)*32;
    int tid = threadIdx.x, tx = tid&7, ty = tid>>3;
    int c0 = cs*(256/CORR_CS), c1 = c0 + (256/CORR_CS);

    float a[4][4];
#pragma unroll
    for (int f=0;f<4;f++)
#pragma unroll
        for (int p=0;p<4;p++) a[f][p]=0.f;

    for (int c=c0;c<c1;++c){
        __syncthreads();
        const float* ic = z1 + (((long)b*256 + c)<<12);
        for (int i=tid;i<44*44;i+=TPB){
            int row=i/44, col=i-row*44;
            int gy=y0-6+row, gx=x0-6+col;
            slds[row*CRS+col] = (gy>=0&&gy<64&&gx>=0&&gx<64)? ic[(gy<<6)+gx] : 0.f;
        }
        if (job<5){
            if (tid<169){
                wl[(tid/13)*16 + (tid%13)] = ze2[((long)(b*5+job)*256 + c)*169 + tid];
            }
        } else {
            if (tid<49) w1l[tid] = ze1[((long)(b*5)*256 + c)*49 + tid];
            else if (tid<65) w0l[tid-49] = ze0[((long)(b*5)*256 + c)*16 + (tid-49)];
        }
        __syncthreads();

        if (job<5){
            for (int r=0;r<13;r++){
                const float* srow = slds + (ty+r)*CRS + tx*4;
                float4 t0 = *(const float4*)(srow);
                float4 t1 = *(const float4*)(srow+4);
                float4 t2v = *(const float4*)(srow+8);
                float4 t3 = *(const float4*)(srow+12);
                float t[16];
                t[0]=t0.x; t[1]=t0.y; t[2]=t0.z; t[3]=t0.w;
                t[4]=t1.x; t[5]=t1.y; t[6]=t1.z; t[7]=t1.w;
                t[8]=t2v.x; t[9]=t2v.y; t[10]=t2v.z; t[11]=t2v.w;
                t[12]=t3.x; t[13]=t3.y; t[14]=t3.z; t[15]=t3.w;
                const float* wp0 = wl + r*16;
                const float* wp1 = wl + (12-r)*16;
                float4 A0=*(const float4*)(wp0), B0=*(const float4*)(wp0+4),
                       C0=*(const float4*)(wp0+8), D0=*(const float4*)(wp0+12);
                float4 A1=*(const float4*)(wp1), B1=*(const float4*)(wp1+4),
                       C1=*(const float4*)(wp1+8), D1=*(const float4*)(wp1+12);
                float w0r[13] = {A0.x,A0.y,A0.z,A0.w,B0.x,B0.y,B0.z,B0.w,C0.x,C0.y,C0.z,C0.w,D0.x};
                float w1r[13] = {A1.x,A1.y,A1.z,A1.w,B1.x,B1.y,B1.z,B1.w,C1.x,C1.y,C1.z,C1.w,D1.x};
#pragma unroll
                for (int k=0;k<13;k++){
                    float wa = w0r[k], wb = w0r[12-k];
                    float wc = w1r[k], wd = w1r[12-k];
#pragma unroll
                    for (int p=0;p<4;p++){
                        float xv = t[p+k];
                        a[0][p] = fmaf(xv, wa, a[0][p]);
                        a[1][p] = fmaf(xv, wb, a[1][p]);
                        a[2][p] = fmaf(xv, wc, a[2][p]);
                        a[3][p] = fmaf(xv, wd, a[3][p]);
                    }
                }
            }
        } else {
#pragma unroll
            for (int i4=0;i4<4;i4++){
                const float* sr = slds + (ty+4+i4)*CRS + tx*4 + 4;
                float t7[7];
#pragma unroll
                for (int q=0;q<7;q++) t7[q]=sr[q];
#pragma unroll
                for (int t=0;t<4;t++){
                    float wv = w0l[i4*4+t];
#pragma unroll
                    for (int p=0;p<4;p++) a[0][p] = fmaf(t7[p+t], wv, a[0][p]);
                }
            }
#pragma unroll
            for (int i7=0;i7<7;i7++){
                const float* sr = slds + (ty+3+i7)*CRS + tx*4 + 3;
                float t10[10];
#pragma unroll
                for (int q=0;q<10;q++) t10[q]=sr[q];
#pragma unroll
                for (int t=0;t<7;t++){
                    float wv = w1l[i7*7+t];
#pragma unroll
                    for (int p=0;p<4;p++) a[1][p] = fmaf(t10[p+t], wv, a[1][p]);
                }
            }
        }
    }

    int y = y0+ty, x = x0+tx*4;
    long base = (long)(b*CORR_CS+cs)*22;
    if (job<5){
#pragma unroll
        for (int f=0;f<4;f++){
            int oc = 2 + f*5 + job;
            *(float4*)(part + ((base+oc)<<12) + (y<<6) + x) =
                make_float4(a[f][0],a[f][1],a[f][2],a[f][3]);
        }
    } else {
        *(float4*)(part + ((base+0)<<12) + (y<<6) + x) = make_float4(a[0][0],a[0][1],a[0][2],a[0][3]);
        *(float4*)(part + ((base+1)<<12) + (y<<6) + x) = make_float4(a[1][0],a[1][1],a[1][2],a[1][3]);
    }
}

__global__ __launch_bounds__(TPB)
void corrred_k(const float* __restrict__ part, float* __restrict__ cm)
{
    long total = (long)2*22*4096;
    long i = (long)blockIdx.x*TPB + threadIdx.x;
    if (i>=total) return;
    int px = (int)(i & 4095); long t = i >> 12;
    int oc = (int)(t % 22); int b = (int)(t / 22);
    float s = 0.f;
    for (int cs=0;cs<CORR_CS;cs++)
        s += part[(((long)(b*CORR_CS+cs)*22 + oc)<<12) + px];
    cm[((long)(b*22+oc)<<12) + px] = s;
}

__global__ __launch_bounds__(TPB)
void atten_k(const float* __restrict__ cmap, float* __restrict__ att, int B, int HW)
{
    int i = blockIdx.x*TPB + threadIdx.x;
    if (i >= B*HW) return;
    int b = i/HW, p = i%HW;
    float s = 0.f;
    for (int m=0;m<22;m++) s += cmap[((long)(b*22+m))*HW + p];
    att[i] = s * (1.f/60.f);
}

// h has only the 278 live channels: [cmap 22][z1*atten 256]
__global__ __launch_bounds__(TPB)
void buildh_k(const float* __restrict__ cmap, const float* __restrict__ z1,
              const float* __restrict__ att, float* __restrict__ h, int B, int HW)
{
    long total = (long)B*278*HW;
    long i = (long)blockIdx.x*TPB + threadIdx.x;
    if (i >= total) return;
    int p = (int)(i % HW); long t = i / HW;
    int ch = (int)(t % 278); int b = (int)(t / 278);
    float v;
    if (ch < 22) v = cmap[((long)(b*22+ch))*HW + p];
    else         v = z1[((long)b*256 + (ch-22))*HW + p] * att[b*HW + p];
    h[i] = v;
}

static inline float acr(int nin, int nout){
    return (float)(((double)(nin-1))/(double)(nout-1));
}

extern "C" void kernel_launch(void* const* d_in, const int* in_sizes, int n_in,
                              void* d_out_v, int out_size, void* d_ws, size_t ws_size,
                              hipStream_t stream)
{
    const float* x0  = (const float*)d_in[0];
    const float* x1  = (const float*)d_in[1];
    const float* x2  = (const float*)d_in[2];
    const float* x3  = (const float*)d_in[3];
    const float* xex = (const float*)d_in[4];
    const float* c1w0=(const float*)d_in[5];  const float* c1b0=(const float*)d_in[6];
    const float* c1w1=(const float*)d_in[7];  const float* c1b1=(const float*)d_in[8];
    const float* c1w2=(const float*)d_in[9];  const float* c1b2=(const float*)d_in[10];
    const float* smw =(const float*)d_in[11]; const float* smb =(const float*)d_in[12];
    const float* fw  =(const float*)d_in[13];
    const float* bng =(const float*)d_in[14]; const float* bnb =(const float*)d_in[15];
    const float* lw1 =(const float*)d_in[16]; const float* lb1 =(const float*)d_in[17];
    const float* lw2 =(const float*)d_in[18]; const float* lb2 =(const float*)d_in[19];
    const float* lw3 =(const float*)d_in[20]; const float* lb3 =(const float*)d_in[21];
    const float* ow1 =(const float*)d_in[22]; const float* ob1 =(const float*)d_in[23];
    const float* ow2 =(const float*)d_in[24]; const float* ob2 =(const float*)d_in[25];
    const float* ow3 =(const float*)d_in[26]; const float* ob3 =(const float*)d_in[27];
    float* dout = (float*)d_out_v;
    float* ws   = (float*)d_ws;

    const int B=2, HW=4096;

    float* f1  = ws;               // 2*256*1024
    float* f2  = f1  + 524288;     // 2*256*256
    float* f3  = f2  + 131072;     // 2*256*64
    float* P1  = f3  + 32768;      // 2*256*4096
    float* P2  = P1  + 2097152;    // 2*256*1024
    float* P3  = P2  + 524288;     // 2*256*256
    float* S2  = P3  + 131072;     // 2*256*1024
    float* S3  = S2  + 524288;     // 2*256*256
    float* CC  = S3  + 131072;     // 2*1024*4096
    float* Z1  = CC  + 8388608;    // 2*256*4096
    float* ZE0 = Z1  + 2097152;    // 2*5*256*16
    float* ZE1 = ZE0 + 40960;      // 2*5*256*49
    float* ZE2 = ZE1 + 125440;     // 2*5*256*169
    float* SUM = ZE2 + 432640;     // 32
    float* CM  = SUM + 32;         // 2*22*4096
    float* Hb  = CM  + 180224;     // 2*278*4096 used
    float* HB1 = Hb  + 2588672;
    float* HB2 = HB1 + 524288;
    float* O164= HB2 + 524288;
    float* OB1 = O164+ 8192;
    float* OB2 = OB1 + 524288;
    float* OFF = OB2 + 524288;
    float* PBF = Hb;               // partial buffer #1 (dead before buildh)
    float* PBC = CC;               // partial buffer #2 (dead after fuse conv)

    float* out1_dst = dout;               // (2,1,512,512)
    float* off_dst  = dout + 524288;      // (2,2,512,512)
    float* att_dst  = dout + 1572864;     // (2,1,64,64)
    float* ze_dst   = dout + 1581056;     // (2,5,256,13,13)

    // 1) FPN lateral 1x1 convs (channel-split, partials in PBF)
    conv_k<1><<<dim3(4,32,B*2), TPB, 0, stream>>>(x1, 512*1024, PBF, 0, c1w0, nullptr, nullptr, 512,256,32,32, M_BIAS, 2);
    convred_k<<<(524288+TPB-1)/TPB, TPB, 0, stream>>>(PBF, f1, 256*1024, c1b0, nullptr, 256, 1024, 2, M_BIAS);
    conv_k<1><<<dim3(1,32,B*8), TPB, 0, stream>>>(x2, 1024*256, PBF, 0, c1w1, nullptr, nullptr, 1024,256,16,16, M_BIAS, 8);
    convred_k<<<(131072+TPB-1)/TPB, TPB, 0, stream>>>(PBF, f2, 256*256, c1b1, nullptr, 256, 256, 8, M_BIAS);
    conv_k<1><<<dim3(1,32,B*8), TPB, 0, stream>>>(x3, 2048*64, PBF, 0, c1w2, nullptr, nullptr, 2048,256,8,8, M_BIAS, 8);
    convred_k<<<(32768+TPB-1)/TPB, TPB, 0, stream>>>(PBF, f3, 256*64, c1b2, nullptr, 256, 64, 8, M_BIAS);

    // 2) top-down resize + add
    resize_k<<<(131072+TPB-1)/TPB, TPB, 0, stream>>>(f3, 256*64, 8,8,   P3, 256*256, 16,16, f2, 256*256, 256, B, acr(8,16), acr(8,16));
    resize_k<<<(524288+TPB-1)/TPB, TPB, 0, stream>>>(f2, 256*256, 16,16, P2, 256*1024, 32,32, f1, 256*1024, 256, B, acr(16,32), acr(16,32));
    resize_k<<<(2097152+TPB-1)/TPB, TPB, 0, stream>>>(f1, 256*1024, 32,32, P1, 256*4096, 64,64, x0, 256*4096, 256, B, acr(32,64), acr(32,64));

    // 3) smooth convs (@64 via conv3p pipeline, partials CS=2 -> CC ch0..255)
    conv3p<<<dim3(4,32,B*2), 128, 0, stream>>>(P1, 256*4096, PBF, smw, 256, 256, 2, 256, 0);
    convred_k<<<(2097152+TPB-1)/TPB, TPB, 0, stream>>>(PBF, CC, 1024*4096, smb, nullptr, 256, 4096, 2, M_BIAS);
    conv_k<3><<<dim3(4,32,B*2), TPB, 0, stream>>>(P2, 256*1024, PBF, 0, smw, nullptr, nullptr, 256,256,32,32, M_BIAS, 2);
    convred_k<<<(524288+TPB-1)/TPB, TPB, 0, stream>>>(PBF, S2, 256*1024, smb, nullptr, 256, 1024, 2, M_BIAS);
    conv_k<3><<<dim3(1,32,B*4), TPB, 0, stream>>>(P3, 256*256, PBF, 0, smw, nullptr, nullptr, 256,256,16,16, M_BIAS, 4);
    convred_k<<<(131072+TPB-1)/TPB, TPB, 0, stream>>>(PBF, S3, 256*256, smb, nullptr, 256, 256, 4, M_BIAS);

    // 4) resize into concat slices
    resize_k<<<(2097152+TPB-1)/TPB, TPB, 0, stream>>>(S2, 256*1024, 32,32, CC+256*4096, 1024*4096, 64,64, nullptr,0, 256, B, acr(32,64), acr(32,64));
    resize_k<<<(2097152+TPB-1)/TPB, TPB, 0, stream>>>(S3, 256*256,  16,16, CC+512*4096, 1024*4096, 64,64, nullptr,0, 256, B, acr(16,64), acr(16,64));
    resize_k<<<(2097152+TPB-1)/TPB, TPB, 0, stream>>>(f3, 256*64,   8,8,   CC+768*4096, 1024*4096, 64,64, nullptr,0, 256, B, acr(8,64),  acr(8,64));

    // 5) fuse conv + bn + relu -> Z1 (conv3p CS=2, partials in PBF)
    conv3p<<<dim3(4,32,B*2), 128, 0, stream>>>(CC, 1024*4096, PBF, fw, 1024, 256, 2, 1024, 0);
    convred_k<<<(2097152+TPB-1)/TPB, TPB, 0, stream>>>(PBF, Z1, 256*4096, bng, bnb, 256, 4096, 2, M_BN_RELU);

    // 6) ROI pooling + normalize
    roi_k<<<B*5, TPB, 0, stream>>>(Z1, xex, ZE0, SUM+0,  4,  5, 256, 64, 64);
    roi_k<<<B*5, TPB, 0, stream>>>(Z1, xex, ZE1, SUM+10, 7,  5, 256, 64, 64);
    roi_k<<<B*5, TPB, 0, stream>>>(Z1, xex, ZE2, SUM+20, 13, 5, 256, 64, 64);
    norm_k<<<(40960+TPB-1)/TPB,  TPB, 0, stream>>>(ZE0, SUM+0,  256*16,  40960,  nullptr);
    norm_k<<<(125440+TPB-1)/TPB, TPB, 0, stream>>>(ZE1, SUM+10, 256*49,  125440, nullptr);
    norm_k<<<(432640+TPB-1)/TPB, TPB, 0, stream>>>(ZE2, SUM+20, 256*169, 432640, ze_dst);

    // 7) correlation (job-split), partials in PBC
    corr3_k<<<dim3(4,6,B*CORR_CS), TPB, 0, stream>>>(Z1, ZE0, ZE1, ZE2, PBC);
    corrred_k<<<(180224+TPB-1)/TPB, TPB, 0, stream>>>(PBC, CM);

    // 8) atten
    atten_k<<<(B*HW+TPB-1)/TPB, TPB, 0, stream>>>(CM, att_dst, B, HW);

    // 9) build h (278 live channels)
    buildh_k<<<((long)B*278*HW+TPB-1)/TPB, TPB, 0, stream>>>(CM, Z1, att_dst, Hb, B, HW);

    // 10) ll chain (ll1 via conv3p CS=8)
    conv3p<<<dim3(4,8,B*8), 128, 0, stream>>>(Hb, 278*4096, PBC, lw1, 278, 64, 8, 316, 1);
    convred_k<<<(524288+TPB-1)/TPB, TPB, 0, stream>>>(PBC, HB1, 64*4096, lb1, nullptr, 64, 4096, 8, M_BIAS_RELU);
    conv3_64<<<dim3(2,16,B*8), TPB, 0, stream>>>(HB1, 64*4096, PBC, 0, lw2, nullptr, nullptr, 64,64, M_BIAS_RELU, 8, 64, 0);
    convred_k<<<(524288+TPB-1)/TPB, TPB, 0, stream>>>(PBC, HB2, 64*4096, lb2, nullptr, 64, 4096, 8, M_BIAS_RELU);
    conv_k<1><<<dim3(16,1,B), TPB, 0, stream>>>(HB2, 64*4096, O164, 1*4096, lw3, lb3, nullptr, 64,1,64,64, M_BIAS_RELU, 1);

    // 11) offset chain (of1 via conv3p CS=8)
    conv3p<<<dim3(4,8,B*8), 128, 0, stream>>>(Z1, 256*4096, PBC, ow1, 256, 64, 8, 256, 0);
    convred_k<<<(524288+TPB-1)/TPB, TPB, 0, stream>>>(PBC, OB1, 64*4096, ob1, nullptr, 64, 4096, 8, M_BIAS_RELU);
    conv3_64<<<dim3(2,16,B*8), TPB, 0, stream>>>(OB1, 64*4096, PBC, 0, ow2, nullptr, nullptr, 64,64, M_BIAS_RELU, 8, 64, 0);
    convred_k<<<(524288+TPB-1)/TPB, TPB, 0, stream>>>(PBC, OB2, 64*4096, ob2, nullptr, 64, 4096, 8, M_BIAS_RELU);
    conv_k<1><<<dim3(16,1,B), TPB, 0, stream>>>(OB2, 64*4096, OFF, 2*4096, ow3, ob3, nullptr, 64,2,64,64, M_SIGAFF, 1);

    // 12) final upsamples
    resize_k<<<(524288+TPB-1)/TPB,  TPB, 0, stream>>>(O164, 4096, 64,64, out1_dst, 262144, 512,512, nullptr,0, 1, B, acr(64,512), acr(64,512));
    resize_k<<<(1048576+TPB-1)/TPB, TPB, 0, stream>>>(OFF,  8192, 64,64, off_dst,  524288, 512,512, nullptr,0, 2, B, acr(64,512), acr(64,512));
}